// Round 1
// baseline (688.420 us; speedup 1.0000x reference)
//
#include <hip/hip_runtime.h>
#include <stdint.h>

// LoRA: y = dropout( (x @ (2 * B@A)^T) ), p=0.1, mask = jax.random.bernoulli(key(42), 0.9)
// x: [4,4096,4096] f32  -> flatten to M=16384 rows, K=4096
// lora_A: [16,4096] f32 ; lora_B: [4096,16] f32 ; out: [16384,4096] f32
//
// Dropout mask (threefry2x32, JAX partitionable layout): counter=(0, i), key=(0,42),
// bits = out0 ^ out1; keep iff u < 0.9f where u = bitcast((bits>>9)|0x3f800000)-1.
// Integer-exact equivalent: keep iff bits < 0xE6666600u
//   (0.9f*2^23 == 7549747 == 0x733333 exactly; f-1.0 is Sterbenz-exact,
//    so u < 0.9f  <=>  (bits>>9) < 0x733333  <=>  bits < 0x733333<<9).
// The 1/0.9 inverted-dropout scale is folded into pass-1's output scale
// (2.0 * (1/0.9)); dropped elements are written as exact 0.0f.

#define M_TOTAL 16384
#define IN_F 4096
#define OUT_F 4096

__device__ __forceinline__ uint32_t tf_bits(uint32_t idx) {
  const uint32_t ks0 = 0u;
  const uint32_t ks1 = 42u;
  const uint32_t ks2 = 0u ^ 42u ^ 0x1BD11BDAu;
  uint32_t x0 = 0u + ks0;      // counts_hi = 0 (N < 2^32)
  uint32_t x1 = idx + ks1;     // counts_lo = flat index
#define TFR(r) { x0 += x1; x1 = (x1 << (r)) | (x1 >> (32 - (r))); x1 ^= x0; }
  TFR(13) TFR(15) TFR(26) TFR(6)   x0 += ks1; x1 += ks2 + 1u;
  TFR(17) TFR(29) TFR(16) TFR(24)  x0 += ks2; x1 += ks0 + 2u;
  TFR(13) TFR(15) TFR(26) TFR(6)   x0 += ks0; x1 += ks1 + 3u;
  TFR(17) TFR(29) TFR(16) TFR(24)  x0 += ks1; x1 += ks2 + 4u;
  TFR(13) TFR(15) TFR(26) TFR(6)   x0 += ks2; x1 += ks0 + 5u;
#undef TFR
  return x0 ^ x1;   // partitionable 32-bit draw: out0 ^ out1
}

// ---------------- Pass 1: t[m, r] = (2/0.9) * sum_i x[m,i] * A[r,i] ----------
// 32-lane groups, each group owns 4 rows (T=4): every A float4 fetched feeds
// 16 FMAs instead of 4 -> A cache traffic 4 GB -> 1 GB (the measured L2 wall).
// 8 rows/wave -> 2048 waves (2/SIMD). Reduction is a pure in-wave butterfly.
__global__ __launch_bounds__(256, 2) void lora_xa_kernel(
    const float* __restrict__ x, const float* __restrict__ A,
    float* __restrict__ t) {
  const int tid = threadIdx.x;
  const int g = tid >> 5;            // group 0..7 (32 lanes each)
  const int c = tid & 31;            // k-chunk lane within group
  const int m0 = blockIdx.x * 32 + g * 4;

  const float4* A4 = (const float4*)A;                       // [16][1024]
  const float4* xr0 = (const float4*)x + (size_t)m0 * 1024;  // 4 rows

  float acc[4][16];
#pragma unroll
  for (int tt = 0; tt < 4; ++tt)
#pragma unroll
    for (int r = 0; r < 16; ++r) acc[tt][r] = 0.0f;

  for (int j = 0; j < 32; ++j) {
    const int f4 = c + j * 32;       // lanes 0..31 -> 512 B contiguous / row
    float4 xv[4];
#pragma unroll
    for (int tt = 0; tt < 4; ++tt) xv[tt] = xr0[tt * 1024 + f4];
#pragma unroll
    for (int r = 0; r < 16; ++r) {
      const float4 av = A4[r * 1024 + f4];
#pragma unroll
      for (int tt = 0; tt < 4; ++tt)
        acc[tt][r] += xv[tt].x * av.x + xv[tt].y * av.y +
                      xv[tt].z * av.z + xv[tt].w * av.w;
    }
  }

  // Butterfly reduce across the 32 lanes of the group (xor offs stay in-group).
#pragma unroll
  for (int off = 1; off <= 16; off <<= 1)
#pragma unroll
    for (int tt = 0; tt < 4; ++tt)
#pragma unroll
      for (int r = 0; r < 16; ++r)
        acc[tt][r] += __shfl_xor(acc[tt][r], off, 64);

  // All 32 lanes hold full sums. Lanes 0-15 write rows m0,m0+1 (col rr);
  // lanes 16-31 write rows m0+2,m0+3. Static-index select via cndmask chain.
  const int rr = c & 15;
  float s[4];
#pragma unroll
  for (int tt = 0; tt < 4; ++tt) {
    float v = acc[tt][0];
#pragma unroll
    for (int r = 1; r < 16; ++r) v = (rr == r) ? acc[tt][r] : v;
    s[tt] = v;
  }
  const bool hi = (c >= 16);
  const float scale = 2.0f / 0.9f;   // SCALING * inverted-dropout 1/keep
  const int mrow = m0 + (hi ? 2 : 0);
  t[(size_t)mrow * 16 + rr]       = (hi ? s[2] : s[0]) * scale;
  t[(size_t)(mrow + 1) * 16 + rr] = (hi ? s[3] : s[1]) * scale;
}

// ---------------- Pass 2: y[m,o] = mask ? sum_r t[m,r] * B[o,r] : 0 ----------
// Block: 64 rows x 1024 cols. Thread owns 4 consecutive cols (B frag in regs),
// loops 64 rows with t staged in LDS (broadcast reads). Dropout is a single
// integer compare per element; scale already folded into t.
__global__ __launch_bounds__(256) void lora_tb_kernel(
    const float* __restrict__ t, const float* __restrict__ B,
    float* __restrict__ y) {
  __shared__ float ts[64 * 16];   // 4 KB
  const int tid = threadIdx.x;
  const int colblk = blockIdx.x & 3;        // 4 col-blocks of 1024
  const int rowblk = blockIdx.x >> 2;       // 256 row-blocks of 64
  const int m0 = rowblk * 64;
  const int o = colblk * 1024 + tid * 4;    // this thread's first column

  // Stage t rows for this block: 1024 floats = 256 float4.
  ((float4*)ts)[tid] = ((const float4*)(t + (size_t)m0 * 16))[tid];

  // Load B[o..o+3][0..15] into registers: 16 float4 (64 VGPRs).
  float4 b[4][4];
#pragma unroll
  for (int c = 0; c < 4; ++c) {
#pragma unroll
    for (int q = 0; q < 4; ++q)
      b[c][q] = ((const float4*)(B + (size_t)(o + c) * 16))[q];
  }
  __syncthreads();

#pragma unroll 2
  for (int mi = 0; mi < 64; ++mi) {
    const int m = m0 + mi;
    float tr[16];
#pragma unroll
    for (int r = 0; r < 16; ++r) tr[r] = ts[mi * 16 + r];  // LDS broadcast

    float accv[4];
#pragma unroll
    for (int c = 0; c < 4; ++c) {
      float s = 0.0f;
#pragma unroll
      for (int q = 0; q < 4; ++q) {
        const float4 bb = b[c][q];
        s += tr[4 * q + 0] * bb.x + tr[4 * q + 1] * bb.y +
             tr[4 * q + 2] * bb.z + tr[4 * q + 3] * bb.w;
      }
      accv[c] = s;
    }

    const uint32_t base = (uint32_t)m * (uint32_t)OUT_F + (uint32_t)o;
    float4 res;
    res.x = (tf_bits(base + 0u) < 0xE6666600u) ? accv[0] : 0.0f;
    res.y = (tf_bits(base + 1u) < 0xE6666600u) ? accv[1] : 0.0f;
    res.z = (tf_bits(base + 2u) < 0xE6666600u) ? accv[2] : 0.0f;
    res.w = (tf_bits(base + 3u) < 0xE6666600u) ? accv[3] : 0.0f;
    ((float4*)y)[((size_t)m * OUT_F + o) >> 2] = res;
  }
}

extern "C" void kernel_launch(void* const* d_in, const int* in_sizes, int n_in,
                              void* d_out, int out_size, void* d_ws, size_t ws_size,
                              hipStream_t stream) {
  const float* x = (const float*)d_in[0];   // [16384, 4096]
  const float* A = (const float*)d_in[1];   // [16, 4096]
  const float* B = (const float*)d_in[2];   // [4096, 16]
  float* y = (float*)d_out;                 // [16384, 4096]
  float* t = (float*)d_ws;                  // [16384, 16] scratch (1 MB)

  lora_xa_kernel<<<M_TOTAL / 32, 256, 0, stream>>>(x, A, t);
  lora_tb_kernel<<<(M_TOTAL / 64) * (OUT_F / 1024), 256, 0, stream>>>(t, B, y);
}